// Round 2
// baseline (726.172 us; speedup 1.0000x reference)
//
#include <hip/hip_runtime.h>
#include <hip/hip_bf16.h>

#define DIM 512

typedef __bf16 bf16x8 __attribute__((ext_vector_type(8)));
typedef float f32x16 __attribute__((ext_vector_type(16)));

union B128 { uint4 u; bf16x8 v; unsigned short us[8]; };

__device__ __forceinline__ unsigned short f2bf(float f) {
    union { __hip_bfloat16 b; unsigned short u; } c;
    c.b = __float2bfloat16(f);
    return c.u;
}

// S[e][d] = bf16(A[e][d] + A[d][e])
__global__ void prep_s_kernel(const float* __restrict__ A,
                              unsigned short* __restrict__ S) {
    int i = blockIdx.x * 256 + threadIdx.x;   // 0 .. 512*512-1
    int e = i >> 9;
    int d = i & 511;
    S[i] = f2bf(A[e * DIM + d] + A[d * DIM + e]);
}

// No LDS, no barriers. Block = 256 threads = 4 waves.
// Wave w: M-strip = blockIdx*64 + 32*(w>>1), N-half = 256*(w&1).
// Each wave: 32 M-rows x 256 N-cols, K=512, register-direct MFMA operands.
// N-half-0 waves also copy q -> out[:,512:] (exact fp32).
__global__ __launch_bounds__(256, 2) void fused_gemm_kernel(
        const float* __restrict__ pq,
        const unsigned short* __restrict__ S,
        float* __restrict__ out) {
    const int t = threadIdx.x;
    const int l = t & 63;
    const int w = t >> 6;        // 0..3
    const int wm = w >> 1;       // 0..1
    const int nh = w & 1;        // 0..1
    const int half = l >> 5;     // 0..1
    const int lane31 = l & 31;
    const int m0 = blockIdx.x * 64;

    const int arow = m0 + 32 * wm + lane31;
    const float* qptr = pq + (size_t)arow * (2 * DIM) + DIM;   // this lane's q row
    float* qout = out + (size_t)arow * (2 * DIM) + DIM;

    f32x16 acc[8];
    #pragma unroll
    for (int nt = 0; nt < 8; ++nt)
        #pragma unroll
        for (int r = 0; r < 16; ++r) acc[nt][r] = 0.0f;

    #pragma unroll 4
    for (int kc = 0; kc < DIM / 16; ++kc) {
        const int k = kc * 16 + half * 8;
        // A fragment: 8 fp32 -> bf16x8 (lane: row=lane31, k..k+7)
        float4 av0 = *(const float4*)(qptr + k);
        float4 av1 = *(const float4*)(qptr + k + 4);
        if (nh == 0) {   // fused exact q-copy
            *(float4*)(qout + k) = av0;
            *(float4*)(qout + k + 4) = av1;
        }
        B128 af;
        af.us[0] = f2bf(av0.x); af.us[1] = f2bf(av0.y);
        af.us[2] = f2bf(av0.z); af.us[3] = f2bf(av0.w);
        af.us[4] = f2bf(av1.x); af.us[5] = f2bf(av1.y);
        af.us[6] = f2bf(av1.z); af.us[7] = f2bf(av1.w);

        #pragma unroll
        for (int nt = 0; nt < 8; ++nt) {
            const int n = nh * 256 + nt * 32 + lane31;   // S row (output col)
            B128 bf;
            bf.u = *(const uint4*)(S + (size_t)n * DIM + k);
            acc[nt] = __builtin_amdgcn_mfma_f32_32x32x16_bf16(af.v, bf.v, acc[nt], 0, 0, 0);
        }
    }

    // Epilogue: out[:, :512] = p + pterm
    // C/D layout (verified): col = tile + lane31, row = 4*half + (r&3) + 8*(r>>2)
    #pragma unroll
    for (int nt = 0; nt < 8; ++nt) {
        const int col = nh * 256 + nt * 32 + lane31;
        #pragma unroll
        for (int r = 0; r < 16; ++r) {
            const int row = m0 + 32 * wm + 4 * half + (r & 3) + 8 * (r >> 2);
            const size_t off = (size_t)row * (2 * DIM) + col;
            out[off] = pq[off] + acc[nt][r];
        }
    }
}

extern "C" void kernel_launch(void* const* d_in, const int* in_sizes, int n_in,
                              void* d_out, int out_size, void* d_ws, size_t ws_size,
                              hipStream_t stream) {
    const float* pq = (const float*)d_in[0];
    const float* A  = (const float*)d_in[1];
    float* out = (float*)d_out;
    unsigned short* S = (unsigned short*)d_ws;   // 512*512*2 = 512 KB scratch

    prep_s_kernel<<<(DIM * DIM) / 256, 256, 0, stream>>>(A, S);
    fused_gemm_kernel<<<65536 / 64, 256, 0, stream>>>(pq, S, out);
}

// Round 3
// 607.546 us; speedup vs baseline: 1.1953x; 1.1953x over previous
//
#include <hip/hip_runtime.h>
#include <hip/hip_bf16.h>

#define DIM 512
#define CHUNK 64              // k-floats staged per chunk
#define NCHUNK (DIM / CHUNK)  // 8
#define QSTRIDE 68            // 64 + 4 pad (shorts) -> 2-way-max LDS banking

typedef __bf16 bf16x8 __attribute__((ext_vector_type(8)));
typedef float f32x16 __attribute__((ext_vector_type(16)));

union B128 { uint4 u; bf16x8 v; unsigned short us[8]; };

__device__ __forceinline__ unsigned short f2bf(float f) {
    union { __hip_bfloat16 b; unsigned short u; } c;
    c.b = __float2bfloat16(f);
    return c.u;
}

// S2[k>>4][n][k&15] = bf16(A[n][k] + A[k][n])  -- k-slab layout so B-frag
// loads are 1 KB fully-contiguous per instruction.
__global__ void prep_s_kernel(const float* __restrict__ A,
                              unsigned short* __restrict__ S2) {
    int i = blockIdx.x * 256 + threadIdx.x;   // 0 .. 262143
    int n = i >> 9;
    int k = i & 511;
    S2[(((k >> 4) * DIM) + n) * 16 + (k & 15)] = f2bf(A[n * DIM + k] + A[k * DIM + n]);
}

// Block = 256 threads = 4 waves, all sharing one 32-row M-strip.
// Wave w owns N-quarter n0 = 128*w (4 MFMA tiles, acc = 64 VGPRs).
// NO barriers: q staged in wave-private LDS slices, S read contiguously
// from L2-resident S2. Wave w==0 fuses the exact fp32 q->out copy.
__global__ __launch_bounds__(256, 3) void fused_gemm_kernel(
        const float* __restrict__ pq,
        const unsigned short* __restrict__ S2,
        float* __restrict__ out) {
    __shared__ __align__(16) unsigned short qlds[4][2][32 * QSTRIDE];

    const int t = threadIdx.x;
    const int l = t & 63;
    const int w = t >> 6;          // N-quarter 0..3
    const int half = l >> 5;
    const int lane31 = l & 31;
    const int m0 = blockIdx.x * 32;
    const int n0 = w * 128;

    // staging: lane covers row m0+(l>>1), 32 consecutive floats at (l&1)*32
    const size_t qoff0 = (size_t)(m0 + (l >> 1)) * (2 * DIM) + DIM + (l & 1) * 32;
    const float* qg = pq + qoff0;
    float* qo = out + qoff0;

    unsigned short* buf0 = &qlds[w][0][0];
    unsigned short* buf1 = &qlds[w][1][0];
    const int wroff = (l >> 1) * QSTRIDE + (l & 1) * 32;
    const int rdoff = lane31 * QSTRIDE + half * 8;

    f32x16 acc[4];
    #pragma unroll
    for (int nt = 0; nt < 4; ++nt)
        #pragma unroll
        for (int r = 0; r < 16; ++r) acc[nt][r] = 0.0f;

    float4 g[8];

    auto load_chunk = [&](int kc) {
        const float* p = qg + kc * CHUNK;
        #pragma unroll
        for (int i = 0; i < 8; ++i) g[i] = *(const float4*)(p + i * 4);
    };
    auto write_chunk = [&](int kc, unsigned short* buf) {
        if (w == 0) {                      // fused exact q-copy (once)
            float* o = qo + kc * CHUNK;
            #pragma unroll
            for (int i = 0; i < 8; ++i) *(float4*)(o + i * 4) = g[i];
        }
        #pragma unroll
        for (int i = 0; i < 4; ++i) {
            B128 b;
            b.us[0] = f2bf(g[2*i].x);   b.us[1] = f2bf(g[2*i].y);
            b.us[2] = f2bf(g[2*i].z);   b.us[3] = f2bf(g[2*i].w);
            b.us[4] = f2bf(g[2*i+1].x); b.us[5] = f2bf(g[2*i+1].y);
            b.us[6] = f2bf(g[2*i+1].z); b.us[7] = f2bf(g[2*i+1].w);
            *(uint4*)&buf[wroff + i * 8] = b.u;
        }
    };
    auto compute_chunk = [&](int kc, const unsigned short* buf) {
        #pragma unroll
        for (int s = 0; s < 4; ++s) {
            B128 a;
            a.u = *(const uint4*)&buf[rdoff + s * 16];
            const int kk = kc * 4 + s;     // global k16-slab index
            #pragma unroll
            for (int nt = 0; nt < 4; ++nt) {
                B128 b;
                b.u = *(const uint4*)(S2 + ((size_t)kk * DIM + n0 + nt * 32 + lane31) * 16 + half * 8);
                acc[nt] = __builtin_amdgcn_mfma_f32_32x32x16_bf16(a.v, b.v, acc[nt], 0, 0, 0);
            }
        }
    };

    // software pipeline, distance 1, wave-private double buffer
    load_chunk(0);
    write_chunk(0, buf0);
    #pragma unroll
    for (int kc = 0; kc < NCHUNK; ++kc) {
        unsigned short* cur = (kc & 1) ? buf1 : buf0;
        unsigned short* nxt = (kc & 1) ? buf0 : buf1;
        if (kc + 1 < NCHUNK) load_chunk(kc + 1);
        compute_chunk(kc, cur);
        if (kc + 1 < NCHUNK) write_chunk(kc + 1, nxt);
    }

    // epilogue: out[:, :512] = p + pterm
    // C/D layout (verified R1/R2): col = lane31, row = 4*half + (r&3) + 8*(r>>2)
    #pragma unroll
    for (int nt = 0; nt < 4; ++nt) {
        const int col = n0 + nt * 32 + lane31;
        #pragma unroll
        for (int r = 0; r < 16; ++r) {
            const int row = m0 + 4 * half + (r & 3) + 8 * (r >> 2);
            const size_t off = (size_t)row * (2 * DIM) + col;
            out[off] = pq[off] + acc[nt][r];
        }
    }
}

extern "C" void kernel_launch(void* const* d_in, const int* in_sizes, int n_in,
                              void* d_out, int out_size, void* d_ws, size_t ws_size,
                              hipStream_t stream) {
    const float* pq = (const float*)d_in[0];
    const float* A  = (const float*)d_in[1];
    float* out = (float*)d_out;
    unsigned short* S2 = (unsigned short*)d_ws;   // 512*512*2 = 512 KB scratch

    prep_s_kernel<<<(DIM * DIM) / 256, 256, 0, stream>>>(A, S2);
    fused_gemm_kernel<<<65536 / 32, 256, 0, stream>>>(pq, S2, out);
}